// Round 2
// baseline (233.012 us; speedup 1.0000x reference)
//
#include <hip/hip_runtime.h>
#include <hip/hip_fp16.h>

// Problem constants (reference: N_HEAD=8, D_IN=128, D_KEY=32, B=65536)
#define NB    65536
#define DIN   128
// TEMP = sqrt(32); logits are scaled by 1/TEMP
#define TEMP_INV 0.17677669529663687f

typedef _Float16 f16x8 __attribute__((ext_vector_type(8)));
typedef float    f32x4 __attribute__((ext_vector_type(4)));

__device__ __forceinline__ ushort f2h(float x){
  __half h = __float2half(x);
  return __half_as_ushort(h);
}
__device__ __forceinline__ ushort4 f4h(float4 v){
  ushort4 o; o.x=f2h(v.x); o.y=f2h(v.y); o.z=f2h(v.z); o.w=f2h(v.w); return o;
}

// ---------------------------------------------------------------------------
// Kernel 0a: convert w_h, w_r (f32 [1024][128]) to f16 "LDS image" layout:
//   w16[h][kq][n'][8], kq = i>>3 (input dim i), n' = output dim within head.
// This layout makes kernel B's ds_read_b128 B-fragments fully contiguous
// across the 16 lanes of a fragment (bank-conflict-free).
// 128 blocks x 256 threads; each thread converts one float4 of each matrix.
// ---------------------------------------------------------------------------
__global__ void conv_w_kernel(const float* __restrict__ wh,
                              const float* __restrict__ wr,
                              ushort* __restrict__ w16h,
                              ushort* __restrict__ w16r){
  int t = blockIdx.x * 256 + threadIdx.x;   // 0..32767
  int R  = t >> 5;          // global row 0..1023
  int c4 = t & 31;          // float4 index within row
  int h  = R >> 7, np = R & 127;
  int kq = c4 >> 1, pos = (c4 & 1) * 4;
  int dst = ((h*16 + kq)*128 + np)*8 + pos;
  float4 a = ((const float4*)wh)[t];
  *(ushort4*)&w16h[dst] = f4h(a);
  float4 b = ((const float4*)wr)[t];
  *(ushort4*)&w16r[dst] = f4h(b);
}

// ---------------------------------------------------------------------------
// Kernel 0b: CW[n][i] = sum_d k[kk][d] * w[h*128+d][i],  n = h*32+kk.
// Output f16 image [kq=i>>3][256][8] (chunk-major for kernel A staging).
// Grid 64 = (matrix m) x (head h) x (i-quarter iq); 256 threads.
// ---------------------------------------------------------------------------
__global__ void make_cw_kernel(const float* __restrict__ wh, const float* __restrict__ wr,
                               const float* __restrict__ kh, const float* __restrict__ kr,
                               ushort* __restrict__ cwh, ushort* __restrict__ cwr){
  int m  = blockIdx.x >> 5;
  int h  = (blockIdx.x >> 2) & 7;
  int iq = blockIdx.x & 3;
  const float* w = m ? wr : wh;
  const float* k = m ? kr : kh;
  ushort* cw = m ? cwr : cwh;

  extern __shared__ char smem[];
  float* w_s = (float*)smem;        // [128 d][32 i_local]
  float* k_s = w_s + 128*32;        // [32 kk][128 d]
  int t = threadIdx.x;

  #pragma unroll
  for (int p=0;p<4;p++){            // stage w columns iq*32..iq*32+31
    int f = t + p*256;              // 1024 float4
    int d = f >> 3, c4 = f & 7;
    *(float4*)&w_s[d*32 + c4*4] =
        *(const float4*)&w[(size_t)(h*128 + d)*128 + iq*32 + c4*4];
  }
  #pragma unroll
  for (int p=0;p<4;p++){            // stage k fully (32*128 floats)
    int f = t + p*256;
    ((float4*)k_s)[f] = ((const float4*)k)[f];
  }
  __syncthreads();

  int il  = t & 31;
  int kk0 = t >> 5;                 // 0..7
  float acc[4] = {0.f,0.f,0.f,0.f};
  for (int d=0; d<128; d++){
    float wv = w_s[d*32 + il];
    #pragma unroll
    for (int j=0;j<4;j++) acc[j] += k_s[(kk0 + 8*j)*128 + d] * wv;
  }
  int i = iq*32 + il;
  #pragma unroll
  for (int j=0;j<4;j++){
    int n = h*32 + kk0 + 8*j;
    cw[(size_t)((i>>3)*256 + n)*8 + (i&7)] = f2h(acc[j]);
  }
}

// ---------------------------------------------------------------------------
// Kernel A: per 32-element tile, HK = X_h @ CWh^T, RK = X_r @ CWr^T (f16 MFMA),
// then 8x8 logits/elem -> softmax over 64 -> h_x (row sums), r_x (col sums).
// 2048 blocks x 256 threads (4 waves). LDS ~121 KB -> 1 block/CU.
// ---------------------------------------------------------------------------
__global__ __launch_bounds__(256) void attn_kernel(
    const float* __restrict__ h_emb, const float* __restrict__ r_emb,
    const ushort* __restrict__ cwh, const ushort* __restrict__ cwr,
    float* __restrict__ hx, float* __restrict__ rx){
  extern __shared__ char smem[];
  ushort* xh   = (ushort*)smem;            // [16 kq][32 row][8]  = 4096 halves
  ushort* xr   = xh + 4096;
  ushort* cwcH = xr + 4096;                // [4 kq][256 n][8]    = 8192 halves
  ushort* cwcR = cwcH + 8192;
  float*  hk   = (float*)(smem + 49152);   // [32 e] stride 292: [8 h][36]+pad4
  float*  rk   = hk + 32*292;

  int t  = threadIdx.x;
  int b0 = blockIdx.x * 32;

  // stage X tiles f32 -> f16 image [kq][row][8]
  {
    const float4* gh = (const float4*)h_emb + (size_t)b0*32;
    const float4* gr = (const float4*)r_emb + (size_t)b0*32;
    #pragma unroll
    for (int p=0;p<4;p++){
      int f = t + p*256;                 // 1024 float4 per matrix
      int row = f >> 5, c4 = f & 31;
      int kq = c4 >> 1, pos = (c4 & 1)*4;
      *(ushort4*)&xh[(kq*32 + row)*8 + pos] = f4h(gh[f]);
      *(ushort4*)&xr[(kq*32 + row)*8 + pos] = f4h(gr[f]);
    }
  }

  int l = t & 63, w = t >> 6;
  int g = l >> 4, c = l & 15;

  f32x4 aH[2][4] = {};
  f32x4 aR[2][4] = {};

  for (int kc=0; kc<4; kc++){
    __syncthreads();   // protect previous chunk reads (and cover X staging)
    {
      const ushort4* sH = (const ushort4*)(cwh + (size_t)kc*8192);
      const ushort4* sR = (const ushort4*)(cwr + (size_t)kc*8192);
      #pragma unroll
      for (int p=0;p<8;p++){
        int f = t + p*256;               // 2048 ushort4 per matrix
        *(ushort4*)&cwcH[f*4] = sH[f];
        *(ushort4*)&cwcR[f*4] = sR[f];
      }
    }
    __syncthreads();
    int kqg = kc*4 + g;
    f16x8 ah0 = *(const f16x8*)&xh[(kqg*32 +      c)*8];
    f16x8 ah1 = *(const f16x8*)&xh[(kqg*32 + 16 + c)*8];
    f16x8 ar0 = *(const f16x8*)&xr[(kqg*32 +      c)*8];
    f16x8 ar1 = *(const f16x8*)&xr[(kqg*32 + 16 + c)*8];
    #pragma unroll
    for (int nt=0; nt<4; nt++){
      int n = w*64 + nt*16 + c;
      f16x8 bh = *(const f16x8*)&cwcH[(g*256 + n)*8];
      aH[0][nt] = __builtin_amdgcn_mfma_f32_16x16x32_f16(ah0, bh, aH[0][nt], 0,0,0);
      aH[1][nt] = __builtin_amdgcn_mfma_f32_16x16x32_f16(ah1, bh, aH[1][nt], 0,0,0);
      f16x8 br = *(const f16x8*)&cwcR[(g*256 + n)*8];
      aR[0][nt] = __builtin_amdgcn_mfma_f32_16x16x32_f16(ar0, br, aR[0][nt], 0,0,0);
      aR[1][nt] = __builtin_amdgcn_mfma_f32_16x16x32_f16(ar1, br, aR[1][nt], 0,0,0);
    }
  }

  // scatter accumulators to hk / rk  (C/D layout: col=lane&15, row=(lane>>4)*4+reg)
  #pragma unroll
  for (int mt=0; mt<2; mt++)
    #pragma unroll
    for (int nt=0; nt<4; nt++){
      int n  = w*64 + nt*16 + c;
      int hh = n >> 5, kk = n & 31;
      #pragma unroll
      for (int reg=0; reg<4; reg++){
        int e = mt*16 + g*4 + reg;
        hk[e*292 + hh*36 + kk] = aH[mt][nt][reg];
        rk[e*292 + hh*36 + kk] = aR[mt][nt][reg];
      }
    }
  __syncthreads();

  // softmax: thread handles element e = t>>3, logit row hr = t&7
  int e = t >> 3, hr = t & 7;
  const float* hkr = &hk[e*292 + hr*36];
  float4 hv[8];
  #pragma unroll
  for (int q=0;q<8;q++) hv[q] = *(const float4*)&hkr[q*4];

  float lg[8];
  #pragma unroll
  for (int j=0;j<8;j++){
    const float* rkr = &rk[e*292 + j*36];
    float s = 0.f;
    #pragma unroll
    for (int q=0;q<8;q++){
      float4 rv = *(const float4*)&rkr[q*4];
      s += hv[q].x*rv.x + hv[q].y*rv.y + hv[q].z*rv.z + hv[q].w*rv.w;
    }
    lg[j] = s * TEMP_INV;
  }
  float mx = lg[0];
  #pragma unroll
  for (int j=1;j<8;j++) mx = fmaxf(mx, lg[j]);
  mx = fmaxf(mx, __shfl_xor(mx, 1));
  mx = fmaxf(mx, __shfl_xor(mx, 2));
  mx = fmaxf(mx, __shfl_xor(mx, 4));
  float p[8]; float srow = 0.f;
  #pragma unroll
  for (int j=0;j<8;j++){ p[j] = __expf(lg[j]-mx); srow += p[j]; }
  float S = srow;
  S += __shfl_xor(S, 1); S += __shfl_xor(S, 2); S += __shfl_xor(S, 4);
  float inv = 1.0f / S;
  hx[(size_t)(b0+e)*8 + hr] = srow * inv;

  // column sums via 3-step butterfly across the 8 lanes of the element
  #pragma unroll
  for (int j=0;j<8;j++){
    p[j] += __shfl_xor(p[j], 1);
    p[j] += __shfl_xor(p[j], 2);
    p[j] += __shfl_xor(p[j], 4);
  }
  float cs = p[0];   // static-index select (avoid runtime-indexed array -> scratch)
  #pragma unroll
  for (int j=1;j<8;j++) cs = (hr==j) ? p[j] : cs;
  rx[(size_t)(b0+e)*8 + hr] = cs * inv;
}

// ---------------------------------------------------------------------------
// Kernel B: per 64-element tile: for each head, MFMA h1/r1, weight by
// h_x/r_x, accumulate t; then +residual, LayerNorm, store.
// 1024 blocks x 256 threads (4 waves, 2x2 over [64 rows x 128 cols]).
// LDS ~70 KB -> 2 blocks/CU. A-fragments held in registers across heads.
// ---------------------------------------------------------------------------
__global__ __launch_bounds__(256,2) void fuse_kernel(
    const float* __restrict__ h_emb, const float* __restrict__ r_emb,
    const ushort* __restrict__ w16h, const ushort* __restrict__ w16r,
    const float* __restrict__ hx, const float* __restrict__ rx,
    const float* __restrict__ gamma, const float* __restrict__ beta,
    float* __restrict__ out){
  extern __shared__ char smem[];
  ushort* xh  = (ushort*)smem;            // [16 kq][64 row][8] = 8192 halves
  ushort* xr  = xh + 8192;
  ushort* whc = xr + 8192;                // [8 kq][128 n][8]   = 8192 halves
  ushort* wrc = whc + 8192;
  float* hxs = (float*)(smem + 65536);    // [64][8]
  float* rxs = hxs + 512;
  float* gs  = rxs + 512;                 // [128]
  float* bs  = gs + 128;
  float* red = bs + 128;                  // [64][2 colhalf][2 {s1,s2}]

  int t  = threadIdx.x;
  int b0 = blockIdx.x * 64;

  {
    const float4* gh = (const float4*)h_emb + (size_t)b0*32;
    const float4* gr = (const float4*)r_emb + (size_t)b0*32;
    #pragma unroll
    for (int p=0;p<8;p++){
      int f = t + p*256;                  // 2048 float4 per matrix
      int row = f >> 5, c4 = f & 31;
      int kq = c4 >> 1, pos = (c4&1)*4;
      *(ushort4*)&xh[(kq*64 + row)*8 + pos] = f4h(gh[f]);
      *(ushort4*)&xr[(kq*64 + row)*8 + pos] = f4h(gr[f]);
    }
    if (t < 128)      ((float4*)hxs)[t]     = ((const float4*)(hx + (size_t)b0*8))[t];
    else              ((float4*)rxs)[t-128] = ((const float4*)(rx + (size_t)b0*8))[t-128];
    if (t < 32)       ((float4*)gs)[t]    = ((const float4*)gamma)[t];
    else if (t < 64)  ((float4*)bs)[t-32] = ((const float4*)beta)[t-32];
  }
  __syncthreads();

  int l = t & 63, w = t >> 6;
  int g = l >> 4, c = l & 15;
  int wr_ = w & 1, wc = w >> 1;   // wave tile: rows wr_*32..+32, cols wc*64..+64

  // preload A fragments (reused across all 8 heads): [mt][kstep]
  f16x8 ah[2][4], ar[2][4];
  #pragma unroll
  for (int mt=0; mt<2; mt++)
    #pragma unroll
    for (int ks=0; ks<4; ks++){
      int row = wr_*32 + mt*16 + c;
      ah[mt][ks] = *(const f16x8*)&xh[((ks*4+g)*64 + row)*8];
      ar[mt][ks] = *(const f16x8*)&xr[((ks*4+g)*64 + row)*8];
    }

  f32x4 tacc[2][4] = {};

  for (int h=0; h<8; h++){
    f32x4 h1[2][4] = {};
    f32x4 r1[2][4] = {};
    for (int kc=0; kc<2; kc++){
      __syncthreads();   // protect previous chunk reads
      {
        const ushort4* sH = (const ushort4*)(w16h + (size_t)((h*16 + kc*8)*128)*8);
        const ushort4* sR = (const ushort4*)(w16r + (size_t)((h*16 + kc*8)*128)*8);
        #pragma unroll
        for (int p=0;p<8;p++){
          int f = t + p*256;              // 2048 ushort4 per matrix
          *(ushort4*)&whc[f*4] = sH[f];
          *(ushort4*)&wrc[f*4] = sR[f];
        }
      }
      __syncthreads();
      #pragma unroll
      for (int ks2=0; ks2<2; ks2++){
        int ks = kc*2 + ks2;
        #pragma unroll
        for (int nt=0; nt<4; nt++){
          int n = wc*64 + nt*16 + c;
          f16x8 bh = *(const f16x8*)&whc[((ks2*4+g)*128 + n)*8];
          h1[0][nt] = __builtin_amdgcn_mfma_f32_16x16x32_f16(ah[0][ks], bh, h1[0][nt], 0,0,0);
          h1[1][nt] = __builtin_amdgcn_mfma_f32_16x16x32_f16(ah[1][ks], bh, h1[1][nt], 0,0,0);
          f16x8 br = *(const f16x8*)&wrc[((ks2*4+g)*128 + n)*8];
          r1[0][nt] = __builtin_amdgcn_mfma_f32_16x16x32_f16(ar[0][ks], br, r1[0][nt], 0,0,0);
          r1[1][nt] = __builtin_amdgcn_mfma_f32_16x16x32_f16(ar[1][ks], br, r1[1][nt], 0,0,0);
        }
      }
    }
    // weight by h_x / r_x and accumulate into t
    #pragma unroll
    for (int mt=0; mt<2; mt++)
      #pragma unroll
      for (int reg=0; reg<4; reg++){
        int e = wr_*32 + mt*16 + g*4 + reg;
        float hv = hxs[e*8 + h];
        float rv = rxs[e*8 + h];
        #pragma unroll
        for (int nt=0; nt<4; nt++)
          tacc[mt][nt][reg] += hv*h1[mt][nt][reg] + rv*r1[mt][nt][reg];
      }
  }

  // + residual (re-read h_emb f32 from global; L3-resident)
  #pragma unroll
  for (int mt=0;mt<2;mt++)
    #pragma unroll
    for (int reg=0;reg<4;reg++){
      int e = wr_*32 + mt*16 + g*4 + reg;
      const float* resid = h_emb + (size_t)(b0+e)*128 + wc*64 + c;
      #pragma unroll
      for (int nt=0;nt<4;nt++)
        tacc[mt][nt][reg] += resid[nt*16];
    }

  // row stats: each wave has 64 of the 128 cols; butterfly over 16 lanes,
  // then combine the two col-halves through LDS.
  #pragma unroll
  for (int mt=0;mt<2;mt++)
    #pragma unroll
    for (int reg=0;reg<4;reg++){
      float a = 0.f, b2 = 0.f;
      #pragma unroll
      for (int nt=0;nt<4;nt++){ float v = tacc[mt][nt][reg]; a += v; b2 += v*v; }
      #pragma unroll
      for (int msk=1; msk<16; msk<<=1){
        a  += __shfl_xor(a, msk);
        b2 += __shfl_xor(b2, msk);
      }
      if (c == 0){
        int e = wr_*32 + mt*16 + g*4 + reg;
        red[e*4 + wc*2]     = a;
        red[e*4 + wc*2 + 1] = b2;
      }
    }
  __syncthreads();

  #pragma unroll
  for (int mt=0;mt<2;mt++)
    #pragma unroll
    for (int reg=0;reg<4;reg++){
      int e = wr_*32 + mt*16 + g*4 + reg;
      float S1 = red[e*4 + 0] + red[e*4 + 2];
      float S2 = red[e*4 + 1] + red[e*4 + 3];
      float mu  = S1 * 0.0078125f;             // /128
      float var = S2 * 0.0078125f - mu*mu;
      float rs  = rsqrtf(var + 1e-5f);
      #pragma unroll
      for (int nt=0;nt<4;nt++){
        int col = wc*64 + nt*16 + c;
        out[(size_t)(b0+e)*128 + col] = gs[col]*((tacc[mt][nt][reg]-mu)*rs) + bs[col];
      }
    }
}

// ---------------------------------------------------------------------------
extern "C" void kernel_launch(void* const* d_in, const int* in_sizes, int n_in,
                              void* d_out, int out_size, void* d_ws, size_t ws_size,
                              hipStream_t stream){
  const float* h_emb = (const float*)d_in[0];
  const float* r_emb = (const float*)d_in[1];
  const float* w_h   = (const float*)d_in[2];
  const float* w_r   = (const float*)d_in[3];
  const float* k_h   = (const float*)d_in[4];
  const float* k_r   = (const float*)d_in[5];
  const float* gamma = (const float*)d_in[6];
  const float* beta  = (const float*)d_in[7];
  float* out = (float*)d_out;

  // workspace carve-up (~4.7 MB total)
  ushort* w16h = (ushort*)d_ws;            // 1024*128 halves (f16 image)
  ushort* w16r = w16h + 131072;
  ushort* cwh  = w16r + 131072;            // 256*128 halves (chunk-major image)
  ushort* cwr  = cwh + 32768;
  float*  hx   = (float*)(cwr + 32768);    // [B][8]
  float*  rx   = hx + 524288;

  conv_w_kernel<<<128, 256, 0, stream>>>(w_h, w_r, w16h, w16r);
  make_cw_kernel<<<64, 256, 32768, stream>>>(w_h, w_r, k_h, k_r, cwh, cwr);
  attn_kernel<<<2048, 256, 123904, stream>>>(h_emb, r_emb, cwh, cwr, hx, rx);
  fuse_kernel<<<1024, 256, 71680, stream>>>(h_emb, r_emb, w16h, w16r, hx, rx,
                                            gamma, beta, out);
}

// Round 3
// 209.579 us; speedup vs baseline: 1.1118x; 1.1118x over previous
//
#include <hip/hip_runtime.h>
#include <hip/hip_fp16.h>

// Problem constants (reference: N_HEAD=8, D_IN=128, D_KEY=32, B=65536)
#define TEMP_INV 0.17677669529663687f

typedef _Float16 f16x8 __attribute__((ext_vector_type(8)));
typedef float    f32x4 __attribute__((ext_vector_type(4)));

__device__ __forceinline__ ushort f2h(float x){
  __half h = __float2half(x);
  return __half_as_ushort(h);
}
__device__ __forceinline__ ushort4 f4h(float4 v){
  ushort4 o; o.x=f2h(v.x); o.y=f2h(v.y); o.z=f2h(v.z); o.w=f2h(v.w); return o;
}
__device__ __forceinline__ f16x8 cvt8(float4 a, float4 b){
  f16x8 r;
  r[0]=(_Float16)a.x; r[1]=(_Float16)a.y; r[2]=(_Float16)a.z; r[3]=(_Float16)a.w;
  r[4]=(_Float16)b.x; r[5]=(_Float16)b.y; r[6]=(_Float16)b.z; r[7]=(_Float16)b.w;
  return r;
}
__device__ __forceinline__ f16x8 vscale(f16x8 v, _Float16 s){
  f16x8 r;
  #pragma unroll
  for (int i=0;i<8;i++) r[i] = v[i]*s;
  return r;
}

// ---------------------------------------------------------------------------
// Kernel 0a: convert w_h, w_r (f32 [1024][128]) to f16 fragment image:
//   w16[h][kq][n][8]  (kq = i>>3).  B-frag for (h, kq, n-window) is then a
//   16-lane-contiguous 16B read directly from global (L2-resident).
// ---------------------------------------------------------------------------
__global__ void conv_w_kernel(const float* __restrict__ wh,
                              const float* __restrict__ wr,
                              ushort* __restrict__ w16h,
                              ushort* __restrict__ w16r){
  int t = blockIdx.x * 256 + threadIdx.x;   // 0..32767
  int R  = t >> 5;          // global row 0..1023
  int c4 = t & 31;          // float4 index within row
  int h  = R >> 7, np = R & 127;
  int kq = c4 >> 1, pos = (c4 & 1) * 4;
  int dst = ((h*16 + kq)*128 + np)*8 + pos;
  float4 a = ((const float4*)wh)[t];
  *(ushort4*)&w16h[dst] = f4h(a);
  float4 b = ((const float4*)wr)[t];
  *(ushort4*)&w16r[dst] = f4h(b);
}

// ---------------------------------------------------------------------------
// Kernel 0b: CW[n][i] = sum_d k[kk][d] * w[h*128+d][i],  n = h*32+kk.
// Output f16 image [kq=i>>3][256 n][8].
// ---------------------------------------------------------------------------
__global__ void make_cw_kernel(const float* __restrict__ wh, const float* __restrict__ wr,
                               const float* __restrict__ kh, const float* __restrict__ kr,
                               ushort* __restrict__ cwh, ushort* __restrict__ cwr){
  int m  = blockIdx.x >> 5;
  int h  = (blockIdx.x >> 2) & 7;
  int iq = blockIdx.x & 3;
  const float* w = m ? wr : wh;
  const float* k = m ? kr : kh;
  ushort* cw = m ? cwr : cwh;

  extern __shared__ char smem[];
  float* w_s = (float*)smem;        // [128 d][32 i_local]
  float* k_s = w_s + 128*32;        // [32 kk][128 d]
  int t = threadIdx.x;

  #pragma unroll
  for (int p=0;p<4;p++){
    int f = t + p*256;
    int d = f >> 3, c4 = f & 7;
    *(float4*)&w_s[d*32 + c4*4] =
        *(const float4*)&w[(size_t)(h*128 + d)*128 + iq*32 + c4*4];
  }
  #pragma unroll
  for (int p=0;p<4;p++){
    int f = t + p*256;
    ((float4*)k_s)[f] = ((const float4*)k)[f];
  }
  __syncthreads();

  int il  = t & 31;
  int kk0 = t >> 5;
  float acc[4] = {0.f,0.f,0.f,0.f};
  for (int d=0; d<128; d++){
    float wv = w_s[d*32 + il];
    #pragma unroll
    for (int j=0;j<4;j++) acc[j] += k_s[(kk0 + 8*j)*128 + d] * wv;
  }
  int i = iq*32 + il;
  #pragma unroll
  for (int j=0;j<4;j++){
    int n = h*32 + kk0 + 8*j;
    cw[(size_t)((i>>3)*256 + n)*8 + (i&7)] = f2h(acc[j]);
  }
}

// ---------------------------------------------------------------------------
// Merged kernel: per 32-row tile
//   phase 1: HK/RK = X @ CW^T (B-frags direct from L2) -> scatter -> softmax
//            -> h_x/r_x to LDS
//   phase 2: tacc = sum_h [ (hv.X_h)@Wh^T + (rv.X_r)@Wr^T ]  (A pre-scaled,
//            B-frags direct from L2, no LDS, no barriers in the loop)
//   epilogue: +residual, LayerNorm, store.
// 2048 blocks x 256 threads. LDS 78 KB -> 2 blocks/CU.
// ---------------------------------------------------------------------------
__global__ __launch_bounds__(256,2) void xattn_fused(
    const float* __restrict__ h_emb, const float* __restrict__ r_emb,
    const ushort* __restrict__ w16h, const ushort* __restrict__ w16r,
    const ushort* __restrict__ cwh,  const ushort* __restrict__ cwr,
    const float* __restrict__ gamma, const float* __restrict__ beta,
    float* __restrict__ out)
{
  extern __shared__ char smem[];
  float* hk  = (float*)smem;        // [32 e][8 h][36] stride 292 (+4 pad)
  float* rk  = hk + 32*292;
  float* hxs = rk + 32*292;         // [32 e] stride 9
  float* rxs = hxs + 288;
  float* red = rxs + 288;           // [32 row][8]

  const int t  = threadIdx.x;
  const int b0 = blockIdx.x * 32;
  const int l  = t & 63, w = t >> 6;
  const int g  = l >> 4, c = l & 15;

  // ---- A fragments straight from global f32, convert to f16 -------------
  f16x8 ah[2][4], ar[2][4];
  #pragma unroll
  for (int mt=0; mt<2; mt++){
    const float* ph = h_emb + ((size_t)(b0 + mt*16 + c))*128 + g*8;
    const float* pr = r_emb + ((size_t)(b0 + mt*16 + c))*128 + g*8;
    #pragma unroll
    for (int ks=0; ks<4; ks++){
      float4 lo  = *(const float4*)(ph + ks*32);
      float4 hi  = *(const float4*)(ph + ks*32 + 4);
      ah[mt][ks] = cvt8(lo, hi);
      float4 lo2 = *(const float4*)(pr + ks*32);
      float4 hi2 = *(const float4*)(pr + ks*32 + 4);
      ar[mt][ks] = cvt8(lo2, hi2);
    }
  }

  // ---- phase 1: HK/RK for n in [w*64, w*64+64) ---------------------------
  f32x4 aH[2][4] = {};
  f32x4 aR[2][4] = {};
  {
    const ushort* pH = cwh + ((size_t)g*256 + w*64 + c)*8;
    const ushort* pR = cwr + ((size_t)g*256 + w*64 + c)*8;
    #pragma unroll
    for (int ks=0; ks<4; ks++){
      #pragma unroll
      for (int nt=0; nt<4; nt++){
        f16x8 bh = *(const f16x8*)(pH + ((size_t)ks*1024 + nt*16)*8);
        f16x8 br = *(const f16x8*)(pR + ((size_t)ks*1024 + nt*16)*8);
        aH[0][nt] = __builtin_amdgcn_mfma_f32_16x16x32_f16(ah[0][ks], bh, aH[0][nt],0,0,0);
        aH[1][nt] = __builtin_amdgcn_mfma_f32_16x16x32_f16(ah[1][ks], bh, aH[1][nt],0,0,0);
        aR[0][nt] = __builtin_amdgcn_mfma_f32_16x16x32_f16(ar[0][ks], br, aR[0][nt],0,0,0);
        aR[1][nt] = __builtin_amdgcn_mfma_f32_16x16x32_f16(ar[1][ks], br, aR[1][nt],0,0,0);
      }
    }
  }

  // scatter (C/D layout: col=lane&15, row=(lane>>4)*4+reg)
  #pragma unroll
  for (int mt=0; mt<2; mt++)
    #pragma unroll
    for (int nt=0; nt<4; nt++){
      int n  = w*64 + nt*16 + c;
      int hh = n >> 5, kk = n & 31;
      #pragma unroll
      for (int reg=0; reg<4; reg++){
        int e = mt*16 + g*4 + reg;
        hk[e*292 + hh*36 + kk] = aH[mt][nt][reg];
        rk[e*292 + hh*36 + kk] = aR[mt][nt][reg];
      }
    }
  __syncthreads();

  // ---- softmax: thread = (element e, logit row hr) ----------------------
  {
    int e = t >> 3, hr = t & 7;
    const float* hkr = &hk[e*292 + hr*36];
    float4 hv4[8];
    #pragma unroll
    for (int q=0;q<8;q++) hv4[q] = *(const float4*)&hkr[q*4];

    float lg[8];
    #pragma unroll
    for (int j=0;j<8;j++){
      const float* rkr = &rk[e*292 + j*36];
      float s = 0.f;
      #pragma unroll
      for (int q=0;q<8;q++){
        float4 rv = *(const float4*)&rkr[q*4];
        s += hv4[q].x*rv.x + hv4[q].y*rv.y + hv4[q].z*rv.z + hv4[q].w*rv.w;
      }
      lg[j] = s * TEMP_INV;
    }
    float mx = lg[0];
    #pragma unroll
    for (int j=1;j<8;j++) mx = fmaxf(mx, lg[j]);
    mx = fmaxf(mx, __shfl_xor(mx, 1));
    mx = fmaxf(mx, __shfl_xor(mx, 2));
    mx = fmaxf(mx, __shfl_xor(mx, 4));
    float p[8]; float srow = 0.f;
    #pragma unroll
    for (int j=0;j<8;j++){ p[j] = __expf(lg[j]-mx); srow += p[j]; }
    float S = srow;
    S += __shfl_xor(S, 1); S += __shfl_xor(S, 2); S += __shfl_xor(S, 4);
    float inv = 1.0f / S;
    hxs[e*9 + hr] = srow * inv;

    #pragma unroll
    for (int j=0;j<8;j++){
      p[j] += __shfl_xor(p[j], 1);
      p[j] += __shfl_xor(p[j], 2);
      p[j] += __shfl_xor(p[j], 4);
    }
    float cs = p[0];
    #pragma unroll
    for (int j=1;j<8;j++) cs = (hr==j) ? p[j] : cs;
    rxs[e*9 + hr] = cs * inv;
  }
  __syncthreads();

  // ---- phase 2: cols [w*32, w*32+32), A pre-scaled by hv/rv -------------
  const int col0 = w*32;
  f32x4 tacc[2][2] = {};
  {
    const ushort* bH = w16h + ((size_t)g*128 + col0 + c)*8;
    const ushort* bR = w16r + ((size_t)g*128 + col0 + c)*8;
    #pragma unroll
    for (int h=0; h<8; h++){
      _Float16 h0 = (_Float16)hxs[c*9 + h];
      _Float16 h1 = (_Float16)hxs[(16+c)*9 + h];
      _Float16 r0 = (_Float16)rxs[c*9 + h];
      _Float16 r1 = (_Float16)rxs[(16+c)*9 + h];
      #pragma unroll
      for (int ks=0; ks<4; ks++){
        size_t off = (size_t)(h*16 + ks*4)*128*8;
        f16x8 a0 = vscale(ah[0][ks], h0);
        f16x8 a1 = vscale(ah[1][ks], h1);
        f16x8 b0v = *(const f16x8*)(bH + off);
        f16x8 b1v = *(const f16x8*)(bH + off + 16*8);
        tacc[0][0] = __builtin_amdgcn_mfma_f32_16x16x32_f16(a0, b0v, tacc[0][0],0,0,0);
        tacc[1][0] = __builtin_amdgcn_mfma_f32_16x16x32_f16(a1, b0v, tacc[1][0],0,0,0);
        tacc[0][1] = __builtin_amdgcn_mfma_f32_16x16x32_f16(a0, b1v, tacc[0][1],0,0,0);
        tacc[1][1] = __builtin_amdgcn_mfma_f32_16x16x32_f16(a1, b1v, tacc[1][1],0,0,0);
        f16x8 c0 = vscale(ar[0][ks], r0);
        f16x8 c1 = vscale(ar[1][ks], r1);
        f16x8 d0v = *(const f16x8*)(bR + off);
        f16x8 d1v = *(const f16x8*)(bR + off + 16*8);
        tacc[0][0] = __builtin_amdgcn_mfma_f32_16x16x32_f16(c0, d0v, tacc[0][0],0,0,0);
        tacc[1][0] = __builtin_amdgcn_mfma_f32_16x16x32_f16(c1, d0v, tacc[1][0],0,0,0);
        tacc[0][1] = __builtin_amdgcn_mfma_f32_16x16x32_f16(c0, d1v, tacc[0][1],0,0,0);
        tacc[1][1] = __builtin_amdgcn_mfma_f32_16x16x32_f16(c1, d1v, tacc[1][1],0,0,0);
      }
    }
  }

  // ---- residual ---------------------------------------------------------
  #pragma unroll
  for (int mt=0; mt<2; mt++)
    #pragma unroll
    for (int reg=0; reg<4; reg++){
      int row = mt*16 + g*4 + reg;
      const float* resid = h_emb + ((size_t)(b0+row))*128 + col0 + c;
      tacc[mt][0][reg] += resid[0];
      tacc[mt][1][reg] += resid[16];
    }

  // ---- LayerNorm row stats: butterfly over 16 lanes, combine 4 waves ----
  #pragma unroll
  for (int mt=0; mt<2; mt++)
    #pragma unroll
    for (int reg=0; reg<4; reg++){
      float v0 = tacc[mt][0][reg], v1 = tacc[mt][1][reg];
      float a = v0 + v1, b2 = v0*v0 + v1*v1;
      #pragma unroll
      for (int m=1; m<16; m<<=1){
        a  += __shfl_xor(a,  m);
        b2 += __shfl_xor(b2, m);
      }
      if (c == 0){
        int row = mt*16 + g*4 + reg;
        red[row*8 + w*2]     = a;
        red[row*8 + w*2 + 1] = b2;
      }
    }
  __syncthreads();

  float gam0 = gamma[col0 + c],      bet0 = beta[col0 + c];
  float gam1 = gamma[col0 + 16 + c], bet1 = beta[col0 + 16 + c];
  #pragma unroll
  for (int mt=0; mt<2; mt++)
    #pragma unroll
    for (int reg=0; reg<4; reg++){
      int row = mt*16 + g*4 + reg;
      float S1 = red[row*8+0] + red[row*8+2] + red[row*8+4] + red[row*8+6];
      float S2 = red[row*8+1] + red[row*8+3] + red[row*8+5] + red[row*8+7];
      float mu  = S1 * 0.0078125f;             // /128
      float var = S2 * 0.0078125f - mu*mu;
      float rs  = rsqrtf(var + 1e-5f);
      float* po = out + ((size_t)(b0+row))*128 + col0 + c;
      po[0]  = gam0*((tacc[mt][0][reg]-mu)*rs) + bet0;
      po[16] = gam1*((tacc[mt][1][reg]-mu)*rs) + bet1;
    }
}

// ---------------------------------------------------------------------------
extern "C" void kernel_launch(void* const* d_in, const int* in_sizes, int n_in,
                              void* d_out, int out_size, void* d_ws, size_t ws_size,
                              hipStream_t stream){
  const float* h_emb = (const float*)d_in[0];
  const float* r_emb = (const float*)d_in[1];
  const float* w_h   = (const float*)d_in[2];
  const float* w_r   = (const float*)d_in[3];
  const float* k_h   = (const float*)d_in[4];
  const float* k_r   = (const float*)d_in[5];
  const float* gamma = (const float*)d_in[6];
  const float* beta  = (const float*)d_in[7];
  float* out = (float*)d_out;

  // workspace carve-up (~640 KB)
  ushort* w16h = (ushort*)d_ws;            // 1024*128 halves (fragment image)
  ushort* w16r = w16h + 131072;
  ushort* cwh  = w16r + 131072;            // 256*128 halves (fragment image)
  ushort* cwr  = cwh + 32768;

  conv_w_kernel<<<128, 256, 0, stream>>>(w_h, w_r, w16h, w16r);
  make_cw_kernel<<<64, 256, 32768, stream>>>(w_h, w_r, k_h, k_r, cwh, cwr);
  xattn_fused<<<2048, 256, 78080, stream>>>(h_emb, r_emb, w16h, w16r,
                                            cwh, cwr, gamma, beta, out);
}